// Round 1
// baseline (257.618 us; speedup 1.0000x reference)
//
#include <hip/hip_runtime.h>

#define BATCH 4
#define NPTS  8192
#define FDIM  64
#define BK    64
#define NT    (NPTS / BK)

typedef _Float16 half_t;
typedef half_t half8 __attribute__((ext_vector_type(8)));
typedef half_t half4 __attribute__((ext_vector_type(4)));
typedef float  f32x4 __attribute__((ext_vector_type(4)));

// ---------------- prep: q[b][n][f] = fp16(x[b][f][n]); vt[b][o][n] = fp16(sum_f x[b][f][n]*w[f][o])
__global__ __launch_bounds__(256) void prep_kernel(
    const float* __restrict__ x, const float* __restrict__ w,
    half_t* __restrict__ q, half_t* __restrict__ vt)
{
    __shared__ float wl[FDIM * FDIM];
    int t = threadIdx.x;
    #pragma unroll
    for (int i = 0; i < (FDIM * FDIM) / 256; ++i)
        wl[i * 256 + t] = w[i * 256 + t];
    __syncthreads();

    int gid = blockIdx.x * 256 + t;          // one (b, n) per thread
    int b = gid >> 13;
    int n = gid & (NPTS - 1);
    const float* xb = x + (size_t)b * FDIM * NPTS + n;

    float acc[FDIM];
    #pragma unroll
    for (int o = 0; o < FDIM; ++o) acc[o] = 0.0f;

    half8* qrow = (half8*)(q + (size_t)gid * FDIM);
    #pragma unroll
    for (int f8 = 0; f8 < 8; ++f8) {
        half8 h;
        #pragma unroll
        for (int j = 0; j < 8; ++j) {
            int f = f8 * 8 + j;
            float xv = xb[(size_t)f * NPTS];          // coalesced across lanes
            h[j] = (half_t)xv;
            const f32x4* wr = (const f32x4*)&wl[f * FDIM];   // broadcast reads (conflict-free)
            #pragma unroll
            for (int o4 = 0; o4 < FDIM / 4; ++o4) {
                f32x4 wv = wr[o4];
                acc[o4*4+0] += xv * wv[0];
                acc[o4*4+1] += xv * wv[1];
                acc[o4*4+2] += xv * wv[2];
                acc[o4*4+3] += xv * wv[3];
            }
        }
        qrow[f8] = h;
    }
    half_t* vb = vt + (size_t)b * FDIM * NPTS + n;
    #pragma unroll
    for (int o = 0; o < FDIM; ++o)
        vb[(size_t)o * NPTS] = (half_t)acc[o];        // coalesced across lanes
}

// ---------------- flash attention: out[b][o][n] = (softmax(X^T X) @ support)^T
// swapped-operand scheme: S^T = mfma(K, Q^T); O^T = mfma(V^T, P^T)
__global__ __launch_bounds__(128) void flash_kernel(
    const half_t* __restrict__ qk, const half_t* __restrict__ vt,
    float* __restrict__ out)
{
    __shared__ half_t kl[BK * FDIM];       // K tile,  rows = kv, swizzled granules
    __shared__ half_t vl[FDIM * BK];       // V^T tile, rows = o,  swizzled granules
    __shared__ half_t pl[2][32 * 72];      // per-wave P[q][k], row stride 72 (144B, no conflicts)

    int t    = threadIdx.x;
    int lane = t & 63;
    int w    = t >> 6;                     // wave 0..1
    int l15  = lane & 15;
    int lg   = lane >> 4;                  // lane group 0..3

    int blk0 = blockIdx.x;                           // 512 wgs
    int blk  = (blk0 & 7) * 64 + (blk0 >> 3);        // XCD swizzle (bijective, 512 % 8 == 0)
    int b    = blk >> 7;
    int qblk = blk & 127;
    int qbase = qblk * 64 + w * 32;                  // 32 q rows per wave

    // Q fragments (B operand of swapped QK): lane holds Q[qbase + qi*16 + l15][c*32 + lg*8 + j]
    const half_t* qb = qk + ((size_t)b * NPTS + qbase) * FDIM;
    half8 qf[2][2];
    #pragma unroll
    for (int qi = 0; qi < 2; ++qi)
        #pragma unroll
        for (int c = 0; c < 2; ++c)
            qf[qi][c] = *(const half8*)(qb + (size_t)(qi*16 + l15) * FDIM + c*32 + lg*8);

    const half_t* kg = qk + (size_t)b * NPTS * FDIM;
    const half_t* vg = vt + (size_t)b * FDIM * NPTS;

    // staging chunk geometry: 512 16B-chunks per array, 4 per thread
    int crow[4], csg[4], lidx[4];
    #pragma unroll
    for (int i = 0; i < 4; ++i) {
        int c   = t + i * 128;
        crow[i] = c >> 3;                  // row within tile (kv row for K, o row for V^T)
        csg[i]  = c & 7;                   // 16B granule within 128B row
        lidx[i] = crow[i] * FDIM + ((csg[i] ^ (crow[i] & 7)) * 8);   // swizzled LDS elem idx
    }

    // prefetch tile 0 into regs
    half8 st[8];
    #pragma unroll
    for (int i = 0; i < 4; ++i) {
        st[i]     = *(const half8*)(kg + (size_t)crow[i] * FDIM + csg[i] * 8);
        st[4 + i] = *(const half8*)(vg + (size_t)crow[i] * NPTS + csg[i] * 8);
    }

    f32x4 O[4][2];                         // O^T[o-tile][q-half]
    #pragma unroll
    for (int ot = 0; ot < 4; ++ot)
        #pragma unroll
        for (int qi = 0; qi < 2; ++qi)
            #pragma unroll
            for (int r = 0; r < 4; ++r) O[ot][qi][r] = 0.0f;
    float m_[2], l_[2];
    m_[0] = m_[1] = -1e30f;
    l_[0] = l_[1] = 0.0f;

    for (int tile = 0; tile < NT; ++tile) {
        __syncthreads();                   // everyone done reading previous tile
        #pragma unroll
        for (int i = 0; i < 4; ++i) {
            *(half8*)(kl + lidx[i]) = st[i];
            *(half8*)(vl + lidx[i]) = st[4 + i];
        }
        __syncthreads();                   // tile visible
        if (tile + 1 < NT) {               // T14: issue next-tile loads; latency hides under MFMA
            int kb = (tile + 1) * BK;
            #pragma unroll
            for (int i = 0; i < 4; ++i) {
                st[i]     = *(const half8*)(kg + (size_t)(kb + crow[i]) * FDIM + csg[i] * 8);
                st[4 + i] = *(const half8*)(vg + (size_t)crow[i] * NPTS + kb + csg[i] * 8);
            }
        }

        // ---- S^T[ct][qi] = K_tile x Q^T : lane holds S[k = ct*16 + lg*4 + r][q = qi*16 + l15]
        f32x4 S[4][2];
        #pragma unroll
        for (int ct = 0; ct < 4; ++ct)
            #pragma unroll
            for (int qi = 0; qi < 2; ++qi)
                #pragma unroll
                for (int r = 0; r < 4; ++r) S[ct][qi][r] = 0.0f;

        #pragma unroll
        for (int ct = 0; ct < 4; ++ct) {
            int krow = ct * 16 + l15;
            #pragma unroll
            for (int c = 0; c < 2; ++c) {
                int fe = c * 32 + lg * 8;
                half8 kf = *(const half8*)(kl + krow * FDIM + (fe ^ ((krow & 7) * 8)));
                S[ct][0] = __builtin_amdgcn_mfma_f32_16x16x32_f16(kf, qf[0][c], S[ct][0], 0, 0, 0);
                S[ct][1] = __builtin_amdgcn_mfma_f32_16x16x32_f16(kf, qf[1][c], S[ct][1], 0, 0, 0);
            }
        }

        // ---- online softmax per q column (stats per-lane, 2 shuffles per reduce)
        #pragma unroll
        for (int qi = 0; qi < 2; ++qi) {
            float mx = S[0][qi][0];
            #pragma unroll
            for (int ct = 0; ct < 4; ++ct)
                #pragma unroll
                for (int r = 0; r < 4; ++r)
                    mx = fmaxf(mx, S[ct][qi][r]);
            mx = fmaxf(mx, __shfl_xor(mx, 16));
            mx = fmaxf(mx, __shfl_xor(mx, 32));
            float mn   = fmaxf(m_[qi], mx);
            float corr = __expf(m_[qi] - mn);
            m_[qi] = mn;
            float s = 0.0f;
            #pragma unroll
            for (int ct = 0; ct < 4; ++ct) {
                #pragma unroll
                for (int r = 0; r < 4; ++r) {
                    float p = __expf(S[ct][qi][r] - mn);
                    S[ct][qi][r] = p;
                    s += p;
                }
            }
            s += __shfl_xor(s, 16);
            s += __shfl_xor(s, 32);
            l_[qi] = l_[qi] * corr + s;
            #pragma unroll
            for (int ot = 0; ot < 4; ++ot)
                #pragma unroll
                for (int r = 0; r < 4; ++r)
                    O[ot][qi][r] *= corr;
            // P[q][k]: 4 contiguous k per lane -> one b64 store
            #pragma unroll
            for (int ct = 0; ct < 4; ++ct) {
                half4 pv;
                #pragma unroll
                for (int r = 0; r < 4; ++r) pv[r] = (half_t)S[ct][qi][r];
                *(half4*)(&pl[w][(qi*16 + l15) * 72 + ct*16 + lg*4]) = pv;
            }
        }
        asm volatile("s_waitcnt lgkmcnt(0)" ::: "memory");
        __builtin_amdgcn_sched_barrier(0);

        // ---- O^T += V^T x P^T : A-frag from vl rows (o), B-frag from pl rows (q)
        #pragma unroll
        for (int c = 0; c < 2; ++c) {
            half8 pb0 = *(const half8*)(&pl[w][(0 * 16 + l15) * 72 + c*32 + lg*8]);
            half8 pb1 = *(const half8*)(&pl[w][(1 * 16 + l15) * 72 + c*32 + lg*8]);
            #pragma unroll
            for (int ot = 0; ot < 4; ++ot) {
                int orow = ot * 16 + l15;
                int fe   = c * 32 + lg * 8;
                half8 vf = *(const half8*)(vl + orow * FDIM + (fe ^ ((orow & 7) * 8)));
                O[ot][0] = __builtin_amdgcn_mfma_f32_16x16x32_f16(vf, pb0, O[ot][0], 0, 0, 0);
                O[ot][1] = __builtin_amdgcn_mfma_f32_16x16x32_f16(vf, pb1, O[ot][1], 0, 0, 0);
            }
        }
    }

    // ---- epilogue: out[b][o][qglobal] = O^T / l   (64B-contiguous segments per lane group)
    size_t obase = (size_t)b * FDIM * NPTS + qbase;
    #pragma unroll
    for (int qi = 0; qi < 2; ++qi) {
        float inv = 1.0f / l_[qi];
        #pragma unroll
        for (int ot = 0; ot < 4; ++ot)
            #pragma unroll
            for (int r = 0; r < 4; ++r) {
                int o = ot * 16 + lg * 4 + r;
                out[obase + (size_t)o * NPTS + qi * 16 + l15] = O[ot][qi][r] * inv;
            }
    }
}

extern "C" void kernel_launch(void* const* d_in, const int* in_sizes, int n_in,
                              void* d_out, int out_size, void* d_ws, size_t ws_size,
                              hipStream_t stream) {
    (void)in_sizes; (void)n_in; (void)out_size; (void)ws_size;
    const float* x = (const float*)d_in[0];
    const float* w = (const float*)d_in[1];
    float* out = (float*)d_out;

    half_t* q  = (half_t*)d_ws;                                  // [B][N][64]   4 MB
    half_t* vt = q + (size_t)BATCH * NPTS * FDIM;                // [B][64][N]   4 MB

    prep_kernel<<<(BATCH * NPTS) / 256, 256, 0, stream>>>(x, w, q, vt);
    flash_kernel<<<BATCH * (NPTS / 64), 128, 0, stream>>>(q, vt, out);
}

// Round 2
// 133.280 us; speedup vs baseline: 1.9329x; 1.9329x over previous
//
#include <hip/hip_runtime.h>

#define BATCH 4
#define NPTS  8192
#define FDIM  64
#define BK    64
#define NT    (NPTS / BK)

typedef _Float16 half_t;
typedef half_t half8 __attribute__((ext_vector_type(8)));
typedef half_t half4 __attribute__((ext_vector_type(4)));
typedef float  f32x4 __attribute__((ext_vector_type(4)));

// ---------------- prep: q[b][n][f] = fp16(x[b][f][n]); vt[b][o][n] = fp16(sum_f x[b][f][n]*w[f][o])
__global__ __launch_bounds__(128) void prep_kernel(
    const float* __restrict__ x, const float* __restrict__ w,
    half_t* __restrict__ q, half_t* __restrict__ vt)
{
    __shared__ float wl[FDIM * FDIM];
    int t = threadIdx.x;
    #pragma unroll
    for (int i = 0; i < (FDIM * FDIM) / 128; ++i)
        wl[i * 128 + t] = w[i * 128 + t];
    __syncthreads();

    int gid = blockIdx.x * 128 + t;          // one (b, n) per thread
    int b = gid >> 13;
    int n = gid & (NPTS - 1);
    const float* xb = x + (size_t)b * FDIM * NPTS + n;

    float acc[FDIM];
    #pragma unroll
    for (int o = 0; o < FDIM; ++o) acc[o] = 0.0f;

    half8* qrow = (half8*)(q + (size_t)gid * FDIM);
    #pragma unroll
    for (int f8 = 0; f8 < 8; ++f8) {
        half8 h;
        #pragma unroll
        for (int j = 0; j < 8; ++j) {
            int f = f8 * 8 + j;
            float xv = xb[(size_t)f * NPTS];          // coalesced across lanes
            h[j] = (half_t)xv;
            const f32x4* wr = (const f32x4*)&wl[f * FDIM];   // broadcast reads (conflict-free)
            #pragma unroll
            for (int o4 = 0; o4 < FDIM / 4; ++o4) {
                f32x4 wv = wr[o4];
                acc[o4*4+0] += xv * wv[0];
                acc[o4*4+1] += xv * wv[1];
                acc[o4*4+2] += xv * wv[2];
                acc[o4*4+3] += xv * wv[3];
            }
        }
        qrow[f8] = h;
    }
    half_t* vb = vt + (size_t)b * FDIM * NPTS + n;
    #pragma unroll
    for (int o = 0; o < FDIM; ++o)
        vb[(size_t)o * NPTS] = (half_t)acc[o];        // coalesced across lanes
}

// ---------------- flash attention, split-KV.
// swapped-operand scheme: S^T = mfma(K, Q^T); O^T = mfma(V^T, P^T)
// SPLIT>1: write unnormalized partial O + (m,l) to workspace; combine merges.
template<int SPLIT>
__global__ __launch_bounds__(256, 4) void flash_kernel(
    const half_t* __restrict__ qk, const half_t* __restrict__ vt,
    float* __restrict__ out, float* __restrict__ part, float* __restrict__ ml)
{
    constexpr int TPS   = NT / SPLIT;                // KV tiles per split
    constexpr int TOTAL = BATCH * SPLIT * (NPTS / 128);

    __shared__ half_t kl[BK * FDIM];       // K tile,   rows = kv, swizzled granules
    __shared__ half_t vl[FDIM * BK];       // V^T tile, rows = o,  swizzled granules
    __shared__ half_t pl[4][32 * 72];      // per-wave P[q][k], row stride 72 (144B)

    int t    = threadIdx.x;
    int lane = t & 63;
    int w    = t >> 6;                     // wave 0..3
    int l15  = lane & 15;
    int lg   = lane >> 4;                  // lane group 0..3

    int blk0 = blockIdx.x;
    int blk  = (blk0 & 7) * (TOTAL / 8) + (blk0 >> 3);   // XCD swizzle (TOTAL % 8 == 0)
    int qc   = blk & 63;                                 // q chunk (128 rows)
    int rest = blk >> 6;                                 // = b*SPLIT + s
    int s    = rest & (SPLIT - 1);
    int b    = rest / SPLIT;
    int qbase = qc * 128 + w * 32;                       // 32 q rows per wave

    // Q fragments (B operand of swapped QK), pre-scaled by log2(e) -> softmax in base 2
    const half_t* qb = qk + ((size_t)b * NPTS + qbase) * FDIM;
    half8 qf[2][2];
    #pragma unroll
    for (int qi = 0; qi < 2; ++qi)
        #pragma unroll
        for (int c = 0; c < 2; ++c) {
            qf[qi][c] = *(const half8*)(qb + (size_t)(qi*16 + l15) * FDIM + c*32 + lg*8);
            qf[qi][c] = qf[qi][c] * (half_t)1.44269504f;
        }

    const half_t* kg = qk + (size_t)b * NPTS * FDIM;
    const half_t* vg = vt + (size_t)b * FDIM * NPTS;

    // staging geometry: 512 16B-chunks per array, 2 per thread per array
    int crow[2], csg[2], lidx[2];
    #pragma unroll
    for (int i = 0; i < 2; ++i) {
        int c   = t + i * 256;
        crow[i] = c >> 3;                  // row within tile
        csg[i]  = c & 7;                   // 16B granule within 128B row
        lidx[i] = crow[i] * FDIM + ((csg[i] ^ (crow[i] & 7)) * 8);
    }

    // prefetch first tile of this split into regs
    int kb0 = s * TPS * BK;
    half8 st[4];
    #pragma unroll
    for (int i = 0; i < 2; ++i) {
        st[i]     = *(const half8*)(kg + (size_t)(kb0 + crow[i]) * FDIM + csg[i] * 8);
        st[2 + i] = *(const half8*)(vg + (size_t)crow[i] * NPTS + kb0 + csg[i] * 8);
    }

    f32x4 O[4][2];                         // O^T[o-tile][q-half]
    #pragma unroll
    for (int ot = 0; ot < 4; ++ot)
        #pragma unroll
        for (int qi = 0; qi < 2; ++qi)
            #pragma unroll
            for (int r = 0; r < 4; ++r) O[ot][qi][r] = 0.0f;
    float m_[2], l_[2];
    m_[0] = m_[1] = -1e30f;
    l_[0] = l_[1] = 0.0f;

    for (int tt = 0; tt < TPS; ++tt) {
        __syncthreads();                   // everyone done reading previous tile
        #pragma unroll
        for (int i = 0; i < 2; ++i) {
            *(half8*)(kl + lidx[i]) = st[i];
            *(half8*)(vl + lidx[i]) = st[2 + i];
        }
        __syncthreads();                   // tile visible
        if (tt + 1 < TPS) {                // T14: issue next-tile loads early
            int kb = (kb0 + (tt + 1) * BK);
            #pragma unroll
            for (int i = 0; i < 2; ++i) {
                st[i]     = *(const half8*)(kg + (size_t)(kb + crow[i]) * FDIM + csg[i] * 8);
                st[2 + i] = *(const half8*)(vg + (size_t)crow[i] * NPTS + kb + csg[i] * 8);
            }
        }

        // ---- S^T[ct][qi] = K_tile x Q^T : lane holds S[k = ct*16 + lg*4 + r][q = qi*16 + l15]
        f32x4 S[4][2];
        #pragma unroll
        for (int ct = 0; ct < 4; ++ct)
            #pragma unroll
            for (int qi = 0; qi < 2; ++qi)
                #pragma unroll
                for (int r = 0; r < 4; ++r) S[ct][qi][r] = 0.0f;

        #pragma unroll
        for (int ct = 0; ct < 4; ++ct) {
            int krow = ct * 16 + l15;
            #pragma unroll
            for (int c = 0; c < 2; ++c) {
                int fe = c * 32 + lg * 8;
                half8 kf = *(const half8*)(kl + krow * FDIM + (fe ^ ((krow & 7) * 8)));
                S[ct][0] = __builtin_amdgcn_mfma_f32_16x16x32_f16(kf, qf[0][c], S[ct][0], 0, 0, 0);
                S[ct][1] = __builtin_amdgcn_mfma_f32_16x16x32_f16(kf, qf[1][c], S[ct][1], 0, 0, 0);
            }
        }

        // ---- online softmax per q column (base-2 units; stats per-lane, 2 shuffles per reduce)
        #pragma unroll
        for (int qi = 0; qi < 2; ++qi) {
            float mx = S[0][qi][0];
            #pragma unroll
            for (int ct = 0; ct < 4; ++ct)
                #pragma unroll
                for (int r = 0; r < 4; ++r)
                    mx = fmaxf(mx, S[ct][qi][r]);
            mx = fmaxf(mx, __shfl_xor(mx, 16));
            mx = fmaxf(mx, __shfl_xor(mx, 32));
            float mn   = fmaxf(m_[qi], mx);
            float corr = __builtin_amdgcn_exp2f(m_[qi] - mn);
            m_[qi] = mn;
            float sum = 0.0f;
            #pragma unroll
            for (int ct = 0; ct < 4; ++ct) {
                #pragma unroll
                for (int r = 0; r < 4; ++r) {
                    float p = __builtin_amdgcn_exp2f(S[ct][qi][r] - mn);
                    S[ct][qi][r] = p;
                    sum += p;
                }
            }
            sum += __shfl_xor(sum, 16);
            sum += __shfl_xor(sum, 32);
            l_[qi] = l_[qi] * corr + sum;
            #pragma unroll
            for (int ot = 0; ot < 4; ++ot)
                #pragma unroll
                for (int r = 0; r < 4; ++r)
                    O[ot][qi][r] *= corr;
            // P[q][k]: 4 contiguous k per lane -> one b64 store
            #pragma unroll
            for (int ct = 0; ct < 4; ++ct) {
                half4 pv;
                #pragma unroll
                for (int r = 0; r < 4; ++r) pv[r] = (half_t)S[ct][qi][r];
                *(half4*)(&pl[w][(qi*16 + l15) * 72 + ct*16 + lg*4]) = pv;
            }
        }
        asm volatile("s_waitcnt lgkmcnt(0)" ::: "memory");
        __builtin_amdgcn_sched_barrier(0);

        // ---- O^T += V^T x P^T : A-frag from vl rows (o), B-frag from pl rows (q)
        #pragma unroll
        for (int c = 0; c < 2; ++c) {
            half8 pb0 = *(const half8*)(&pl[w][(0 * 16 + l15) * 72 + c*32 + lg*8]);
            half8 pb1 = *(const half8*)(&pl[w][(1 * 16 + l15) * 72 + c*32 + lg*8]);
            #pragma unroll
            for (int ot = 0; ot < 4; ++ot) {
                int orow = ot * 16 + l15;
                int fe   = c * 32 + lg * 8;
                half8 vf = *(const half8*)(vl + orow * FDIM + (fe ^ ((orow & 7) * 8)));
                O[ot][0] = __builtin_amdgcn_mfma_f32_16x16x32_f16(vf, pb0, O[ot][0], 0, 0, 0);
                O[ot][1] = __builtin_amdgcn_mfma_f32_16x16x32_f16(vf, pb1, O[ot][1], 0, 0, 0);
            }
        }
    }

    // ---- epilogue
    if constexpr (SPLIT == 1) {
        size_t obase = (size_t)b * FDIM * NPTS + qbase;
        #pragma unroll
        for (int qi = 0; qi < 2; ++qi) {
            float inv = 1.0f / l_[qi];
            #pragma unroll
            for (int ot = 0; ot < 4; ++ot)
                #pragma unroll
                for (int r = 0; r < 4; ++r) {
                    int o = ot * 16 + lg * 4 + r;
                    out[obase + (size_t)o * NPTS + qi * 16 + l15] = O[ot][qi][r] * inv;
                }
        }
    } else {
        float* pb = part + ((size_t)(s * BATCH + b) * FDIM) * NPTS + qbase;
        #pragma unroll
        for (int qi = 0; qi < 2; ++qi) {
            #pragma unroll
            for (int ot = 0; ot < 4; ++ot)
                #pragma unroll
                for (int r = 0; r < 4; ++r) {
                    int o = ot * 16 + lg * 4 + r;
                    pb[(size_t)o * NPTS + qi * 16 + l15] = O[ot][qi][r];
                }
        }
        if (lg == 0) {
            #pragma unroll
            for (int qi = 0; qi < 2; ++qi) {
                size_t qg = (size_t)qbase + qi * 16 + l15;
                size_t mi = ((size_t)(s * BATCH + b) * NPTS + qg) * 2;
                ml[mi]     = m_[qi];
                ml[mi + 1] = l_[qi];
            }
        }
    }
}

// ---------------- combine partial flash outputs across splits
template<int SPLIT>
__global__ __launch_bounds__(256) void combine_kernel(
    const float* __restrict__ part, const float* __restrict__ ml,
    float* __restrict__ out)
{
    int gid  = blockIdx.x * 256 + threadIdx.x;   // B*FDIM*NPTS threads
    int qi   = gid & (NPTS - 1);
    int rest = gid >> 13;
    int o    = rest & (FDIM - 1);
    int b    = rest >> 6;

    float ms[SPLIT], ls[SPLIT];
    float M = -1e30f;
    #pragma unroll
    for (int s = 0; s < SPLIT; ++s) {
        float2 v = *(const float2*)(ml + ((size_t)(s * BATCH + b) * NPTS + qi) * 2);
        ms[s] = v.x; ls[s] = v.y;
        M = fmaxf(M, v.x);
    }
    float L = 0.0f, acc = 0.0f;
    #pragma unroll
    for (int s = 0; s < SPLIT; ++s) {
        float wgt = __builtin_amdgcn_exp2f(ms[s] - M);
        L   += ls[s] * wgt;
        acc += wgt * part[((size_t)(s * BATCH + b) * FDIM + o) * NPTS + qi];
    }
    out[((size_t)b * FDIM + o) * NPTS + qi] = acc / L;
}

extern "C" void kernel_launch(void* const* d_in, const int* in_sizes, int n_in,
                              void* d_out, int out_size, void* d_ws, size_t ws_size,
                              hipStream_t stream) {
    (void)in_sizes; (void)n_in; (void)out_size;
    const float* x = (const float*)d_in[0];
    const float* w = (const float*)d_in[1];
    float* out = (float*)d_out;

    const size_t qelems = (size_t)BATCH * NPTS * FDIM;
    half_t* q  = (half_t*)d_ws;                    // [B][N][64]   4 MB
    half_t* vt = q + qelems;                       // [B][64][N]   4 MB
    float* part = (float*)((char*)d_ws + 2 * qelems * sizeof(half_t));
    const size_t part_elems = (size_t)BATCH * FDIM * NPTS;          // per split
    const size_t ml_elems   = (size_t)BATCH * NPTS * 2;             // per split
    const size_t base_bytes = 2 * qelems * sizeof(half_t);
    const size_t per_split  = (part_elems + ml_elems) * sizeof(float);

    int split = 1;
    if (ws_size >= base_bytes + 4 * per_split)      split = 4;
    else if (ws_size >= base_bytes + 2 * per_split) split = 2;
    float* ml = part + (size_t)split * part_elems;

    prep_kernel<<<(BATCH * NPTS) / 128, 128, 0, stream>>>(x, w, q, vt);

    if (split == 4) {
        flash_kernel<4><<<BATCH * 4 * (NPTS / 128), 256, 0, stream>>>(q, vt, out, part, ml);
        combine_kernel<4><<<(BATCH * FDIM * NPTS) / 256, 256, 0, stream>>>(part, ml, out);
    } else if (split == 2) {
        flash_kernel<2><<<BATCH * 2 * (NPTS / 128), 256, 0, stream>>>(q, vt, out, part, ml);
        combine_kernel<2><<<(BATCH * FDIM * NPTS) / 256, 256, 0, stream>>>(part, ml, out);
    } else {
        flash_kernel<1><<<BATCH * 1 * (NPTS / 128), 256, 0, stream>>>(q, vt, out, nullptr, nullptr);
    }
}